// Round 2
// 667.494 us; speedup vs baseline: 1.1582x; 1.1582x over previous
//
#include <hip/hip_runtime.h>

#define NB  64
#define IC  2048
#define ID  16
#define DD  256
#define DDSQ 65536
#define PB  (DDSQ * NB)       // 4,194,304 floats = one full-batch fp32 matrix buffer
#define NSQ 11                // matrix squarings
#define NPI 7                 // finish matvecs: exponent 2^11 * 8 = 16384

typedef __attribute__((ext_vector_type(8))) short          s16x8;  // 8 bf16 (4 VGPRs) MFMA frag
typedef __attribute__((ext_vector_type(4))) float          f32x4;  // MFMA acc
typedef __attribute__((ext_vector_type(4))) unsigned short us4;
typedef __attribute__((ext_vector_type(8))) unsigned short us8;

// fp32 -> bf16 (RNE) and back, via raw bits
__device__ __forceinline__ unsigned short f2b(float f) {
    union { float f; unsigned u; } c; c.f = f;
    const unsigned u = c.u + 0x7FFFu + ((c.u >> 16) & 1u);
    return (unsigned short)(u >> 16);
}
__device__ __forceinline__ float b2f(unsigned short h) {
    union { unsigned u; float f; } c; c.u = ((unsigned)h) << 16;
    return c.f;
}

// FMA into a NAMED float4 (SSA values only — no arrays, nothing to spill)
#define FMA4(c, s, v) { (c).x = fmaf((s), (v).x, (c).x); (c).y = fmaf((s), (v).y, (c).y); \
                        (c).z = fmaf((s), (v).z, (c).z); (c).w = fmaf((s), (v).w, (c).w); }
#define F4Z make_float4(0.f, 0.f, 0.f, 0.f)
#define ADDF4(a, b) { (a).x += (b).x; (a).y += (b).y; (a).z += (b).z; (a).w += (b).w; }
// diagonal-trace contribution of micro-row i held in named float4 ci
#define TRC(ci, i) { if (8*td+(i) == off+4*te+0) ts += (ci).x; \
                     if (8*td+(i) == off+4*te+1) ts += (ci).y; \
                     if (8*td+(i) == off+4*te+2) ts += (ci).z; \
                     if (8*td+(i) == off+4*te+3) ts += (ci).w; }
#define STROW(dst, ci, i) *(float4*)&(dst)[(size_t)(d0 + 8*td + (i)) * DD + e0 + 4*te] = (ci);

// ---------------- stage 1: u[b,c,:] = x[b,c,:] @ W_c (16 batches/block) -----
__global__ __launch_bounds__(256, 4) void u_kernel(const float* __restrict__ caps,
                                                   const float* __restrict__ W,
                                                   float* __restrict__ U) {
    const int c  = blockIdx.x;
    const int b0 = blockIdx.y * 16;
    const int t  = threadIdx.x;
    __shared__ float xsT[ID][16];        // [dim][batch]
    if (t < 64) {
        const int b = t >> 2, q = (t & 3) * 4;
        const float4 x4 = *(const float4*)&caps[((size_t)(b0 + b) * IC + c) * ID + q];
        xsT[q + 0][b] = x4.x; xsT[q + 1][b] = x4.y;
        xsT[q + 2][b] = x4.z; xsT[q + 3][b] = x4.w;
    }
    __syncthreads();
    float a0 = 0.f, a1 = 0.f, a2 = 0.f, a3 = 0.f, a4 = 0.f, a5 = 0.f, a6 = 0.f, a7 = 0.f;
    float a8 = 0.f, a9 = 0.f, a10 = 0.f, a11 = 0.f, a12 = 0.f, a13 = 0.f, a14 = 0.f, a15 = 0.f;
#pragma unroll
    for (int i = 0; i < ID; ++i) {
        const float wi = W[((size_t)c * ID + i) * DD + t];    // coalesced over t
        const float4 x0 = *(const float4*)&xsT[i][0];
        const float4 x1 = *(const float4*)&xsT[i][4];
        const float4 x2 = *(const float4*)&xsT[i][8];
        const float4 x3 = *(const float4*)&xsT[i][12];
        a0  = fmaf(x0.x, wi, a0 );  a1  = fmaf(x0.y, wi, a1 );
        a2  = fmaf(x0.z, wi, a2 );  a3  = fmaf(x0.w, wi, a3 );
        a4  = fmaf(x1.x, wi, a4 );  a5  = fmaf(x1.y, wi, a5 );
        a6  = fmaf(x1.z, wi, a6 );  a7  = fmaf(x1.w, wi, a7 );
        a8  = fmaf(x2.x, wi, a8 );  a9  = fmaf(x2.y, wi, a9 );
        a10 = fmaf(x2.z, wi, a10);  a11 = fmaf(x2.w, wi, a11);
        a12 = fmaf(x3.x, wi, a12);  a13 = fmaf(x3.y, wi, a13);
        a14 = fmaf(x3.z, wi, a14);  a15 = fmaf(x3.w, wi, a15);
    }
    U[((size_t)(b0 +  0) * IC + c) * DD + t] = a0;
    U[((size_t)(b0 +  1) * IC + c) * DD + t] = a1;
    U[((size_t)(b0 +  2) * IC + c) * DD + t] = a2;
    U[((size_t)(b0 +  3) * IC + c) * DD + t] = a3;
    U[((size_t)(b0 +  4) * IC + c) * DD + t] = a4;
    U[((size_t)(b0 +  5) * IC + c) * DD + t] = a5;
    U[((size_t)(b0 +  6) * IC + c) * DD + t] = a6;
    U[((size_t)(b0 +  7) * IC + c) * DD + t] = a7;
    U[((size_t)(b0 +  8) * IC + c) * DD + t] = a8;
    U[((size_t)(b0 +  9) * IC + c) * DD + t] = a9;
    U[((size_t)(b0 + 10) * IC + c) * DD + t] = a10;
    U[((size_t)(b0 + 11) * IC + c) * DD + t] = a11;
    U[((size_t)(b0 + 12) * IC + c) * DD + t] = a12;
    U[((size_t)(b0 + 13) * IC + c) * DD + t] = a13;
    U[((size_t)(b0 + 14) * IC + c) * DD + t] = a14;
    U[((size_t)(b0 + 15) * IC + c) * DD + t] = a15;
}

// ---- stage 2: partial C, 128x64 tile, 8x4 micro (named float4 acc) ---------
// id: low6 = batch (same-XCD tiles per batch); tk = id>>6: tile = tk>>1, kch = tk&1
__global__ __launch_bounds__(256, 4)
void c_kernel(const float* __restrict__ U,
              float* __restrict__ P0, float* __restrict__ P1,
              float* __restrict__ Sc) {
    const int id   = blockIdx.x;
    const int bb   = id & 63;
    const int tk   = id >> 6;            // 0..15
    const int tile = tk >> 1, kch = tk & 1;
    const int tr = tile >> 2, tc = tile & 3;
    const int d0 = tr * 128, e0 = tc * 64;
    const int t  = threadIdx.x;
    const int td = t >> 4, te = t & 15;
    const int sr = t >> 5, sc4 = (t & 31) * 4;   // A staging map
    const int br = t >> 4, bc4 = (t & 15) * 4;   // B staging map
    __shared__ float Ad[32][128];
    __shared__ float Ae[32][64];
    __shared__ float red[256];
    float4 c0 = F4Z, c1 = F4Z, c2 = F4Z, c3 = F4Z;
    float4 c4 = F4Z, c5 = F4Z, c6 = F4Z, c7 = F4Z;
    const float* Ub = U + (size_t)bb * IC * DD;
    const int k0 = kch * (IC / 2);
    for (int kb = k0; kb < k0 + IC / 2; kb += 32) {
        const float4 ra0 = *(const float4*)&Ub[(size_t)(kb +  0 + sr) * DD + d0 + sc4];
        const float4 ra1 = *(const float4*)&Ub[(size_t)(kb +  8 + sr) * DD + d0 + sc4];
        const float4 ra2 = *(const float4*)&Ub[(size_t)(kb + 16 + sr) * DD + d0 + sc4];
        const float4 ra3 = *(const float4*)&Ub[(size_t)(kb + 24 + sr) * DD + d0 + sc4];
        const float4 rb0 = *(const float4*)&Ub[(size_t)(kb +  0 + br) * DD + e0 + bc4];
        const float4 rb1 = *(const float4*)&Ub[(size_t)(kb + 16 + br) * DD + e0 + bc4];
        __syncthreads();
        *(float4*)&Ad[ 0 + sr][sc4] = ra0;
        *(float4*)&Ad[ 8 + sr][sc4] = ra1;
        *(float4*)&Ad[16 + sr][sc4] = ra2;
        *(float4*)&Ad[24 + sr][sc4] = ra3;
        *(float4*)&Ae[ 0 + br][bc4] = rb0;
        *(float4*)&Ae[16 + br][bc4] = rb1;
        __syncthreads();
#pragma unroll 4
        for (int k = 0; k < 32; ++k) {
            const float4 aL = *(const float4*)&Ad[k][8 * td];
            const float4 aH = *(const float4*)&Ad[k][8 * td + 4];
            const float4 b4 = *(const float4*)&Ae[k][4 * te];
            FMA4(c0, aL.x, b4); FMA4(c1, aL.y, b4); FMA4(c2, aL.z, b4); FMA4(c3, aL.w, b4);
            FMA4(c4, aH.x, b4); FMA4(c5, aH.y, b4); FMA4(c6, aH.z, b4); FMA4(c7, aH.w, b4);
        }
    }
    float* Pb = (kch ? P1 : P0) + (size_t)bb * DDSQ;
    STROW(Pb, c0, 0); STROW(Pb, c1, 1); STROW(Pb, c2, 2); STROW(Pb, c3, 3);
    STROW(Pb, c4, 4); STROW(Pb, c5, 5); STROW(Pb, c6, 6); STROW(Pb, c7, 7);
    if ((tc >> 1) == tr) {               // diagonal-overlap tile: fused trace
        const int off = (tc & 1) * 64;
        float ts = 0.f;
        TRC(c0, 0); TRC(c1, 1); TRC(c2, 2); TRC(c3, 3);
        TRC(c4, 4); TRC(c5, 5); TRC(c6, 6); TRC(c7, 7);
        red[t] = ts;
        __syncthreads();
        for (int s = 128; s > 0; s >>= 1) {
            if (t < s) red[t] += red[t + s];
            __syncthreads();
        }
        if (t == 0) atomicAdd(&Sc[bb], red[0]);
    }
}

// ---- E = (D/s)^2 via bf16-split MFMA, 128x64 tile, 4 waves (2x2) -----------
// D symmetric => B-panel rows e0..e0+63 of D give B[k][j] directly in [j][k]
// layout: identical LDS addressing for both operands, no transpose anywhere.
// FIRST: inputs are fp32 P0+P1 (folded, converted in staging); else bf16 hi/lo.
// Outputs always bf16 hi/lo (same bytes as fp32; finish reconstructs hi+lo).
template<bool FIRST>
__global__ __launch_bounds__(256, 2)
void sqm_kernel(const float* __restrict__ F0, const float* __restrict__ F1,
                const unsigned short* __restrict__ Dh, const unsigned short* __restrict__ Dl,
                unsigned short* __restrict__ Eh, unsigned short* __restrict__ El,
                const float* __restrict__ s_in, float* __restrict__ s_out) {
    const int id   = blockIdx.x;          // 512 = 64 batches x 8 tiles
    const int bb   = id & 63;
    const int tile = id >> 6;             // 0..7
    const int tr = tile >> 2, tc = tile & 3;
    const int d0 = tr * 128, e0 = tc * 64;
    const int t    = threadIdx.x;
    const int lane = t & 63, wid = t >> 6;
    const int wm = wid >> 1, wn = wid & 1;            // 2x2 wave grid
    const int fr = lane & 15, kg = lane >> 4;          // frag row/col, k-group

    // pitch 40 (= 32 + 8) bf16 = 80 B: rows r, r+8 share banks (2-way, free)
    __shared__ unsigned short Ah[128][40];
    __shared__ unsigned short Al[128][40];
    __shared__ unsigned short Bh[64][40];
    __shared__ unsigned short Bl[64][40];
    __shared__ float red[256];

    f32x4 acc[4][2] = {};
    const size_t mb = (size_t)bb * DDSQ;
    const float s   = s_in[bb];
    const float inv = 1.f / (s * s);

    for (int kb = 0; kb < DD; kb += 32) {
        if constexpr (FIRST) {
            // fp32 staging: fold P0+P1, convert to hi/lo during LDS write
            float4 va[4], vb[2];
#pragma unroll
            for (int i = 0; i < 4; ++i) {
                const int slot = t + i * 256;              // 0..1023
                const int row = slot >> 3, q = slot & 7;   // 8 float4 per 32-f32 row
                const size_t g = mb + (size_t)(d0 + row) * DD + kb + q * 4;
                float4 x = *(const float4*)&F0[g];
                const float4 y = *(const float4*)&F1[g];
                ADDF4(x, y);
                va[i] = x;
            }
#pragma unroll
            for (int i = 0; i < 2; ++i) {
                const int slot = t + i * 256;              // 0..511
                const int row = slot >> 3, q = slot & 7;
                const size_t g = mb + (size_t)(e0 + row) * DD + kb + q * 4;
                float4 x = *(const float4*)&F0[g];
                const float4 y = *(const float4*)&F1[g];
                ADDF4(x, y);
                vb[i] = x;
            }
            __syncthreads();
#pragma unroll
            for (int i = 0; i < 4; ++i) {
                const int slot = t + i * 256;
                const int row = slot >> 3, q = slot & 7;
                us4 h, l;
                h.x = f2b(va[i].x); l.x = f2b(va[i].x - b2f(h.x));
                h.y = f2b(va[i].y); l.y = f2b(va[i].y - b2f(h.y));
                h.z = f2b(va[i].z); l.z = f2b(va[i].z - b2f(h.z));
                h.w = f2b(va[i].w); l.w = f2b(va[i].w - b2f(h.w));
                *(us4*)&Ah[row][q * 4] = h;
                *(us4*)&Al[row][q * 4] = l;
            }
#pragma unroll
            for (int i = 0; i < 2; ++i) {
                const int slot = t + i * 256;
                const int row = slot >> 3, q = slot & 7;
                us4 h, l;
                h.x = f2b(vb[i].x); l.x = f2b(vb[i].x - b2f(h.x));
                h.y = f2b(vb[i].y); l.y = f2b(vb[i].y - b2f(h.y));
                h.z = f2b(vb[i].z); l.z = f2b(vb[i].z - b2f(h.z));
                h.w = f2b(vb[i].w); l.w = f2b(vb[i].w - b2f(h.w));
                *(us4*)&Bh[row][q * 4] = h;
                *(us4*)&Bl[row][q * 4] = l;
            }
            __syncthreads();
        } else {
            // bf16 staging: straight int4 copies, no conversion
            int4 rah[2], ral[2], rbh, rbl;
#pragma unroll
            for (int i = 0; i < 2; ++i) {
                const int slot = t + i * 256;              // 0..511
                const int row = slot >> 2, q = slot & 3;   // 4 int4 per 32-bf16 row
                const size_t g = mb + (size_t)(d0 + row) * DD + kb + q * 8;
                rah[i] = *(const int4*)&Dh[g];
                ral[i] = *(const int4*)&Dl[g];
            }
            {
                const int row = t >> 2, q = t & 3;
                const size_t g = mb + (size_t)(e0 + row) * DD + kb + q * 8;
                rbh = *(const int4*)&Dh[g];
                rbl = *(const int4*)&Dl[g];
            }
            __syncthreads();
#pragma unroll
            for (int i = 0; i < 2; ++i) {
                const int slot = t + i * 256;
                const int row = slot >> 2, q = slot & 3;
                *(int4*)&Ah[row][q * 8] = rah[i];
                *(int4*)&Al[row][q * 8] = ral[i];
            }
            {
                const int row = t >> 2, q = t & 3;
                *(int4*)&Bh[row][q * 8] = rbh;
                *(int4*)&Bl[row][q * 8] = rbl;
            }
            __syncthreads();
        }

        // fragments: A[m=fr][k=kg*8+j] / B[k=kg*8+j][n=fr] — identical addressing
        s16x8 ah[4], al[4], bh[2], bl[2];
#pragma unroll
        for (int m = 0; m < 4; ++m) {
            const int r = wm * 64 + m * 16 + fr;
            ah[m] = *(const s16x8*)&Ah[r][kg * 8];
            al[m] = *(const s16x8*)&Al[r][kg * 8];
        }
#pragma unroll
        for (int n = 0; n < 2; ++n) {
            const int r = wn * 32 + n * 16 + fr;
            bh[n] = *(const s16x8*)&Bh[r][kg * 8];
            bl[n] = *(const s16x8*)&Bl[r][kg * 8];
        }
#pragma unroll
        for (int m = 0; m < 4; ++m)
#pragma unroll
            for (int n = 0; n < 2; ++n) {
                acc[m][n] = __builtin_amdgcn_mfma_f32_16x16x32_bf16(ah[m], bh[n], acc[m][n], 0, 0, 0);
                acc[m][n] = __builtin_amdgcn_mfma_f32_16x16x32_bf16(ah[m], bl[n], acc[m][n], 0, 0, 0);
                acc[m][n] = __builtin_amdgcn_mfma_f32_16x16x32_bf16(al[m], bh[n], acc[m][n], 0, 0, 0);
            }
    }

    // epilogue: scale, fused trace, split to hi/lo bf16
    float ts = 0.f;
    const int row_l = wm * 64 + (lane >> 4) * 4;     // + m*16 + r
    const int col_l = wn * 32 + fr;                  // + n*16
#pragma unroll
    for (int m = 0; m < 4; ++m)
#pragma unroll
        for (int n = 0; n < 2; ++n)
#pragma unroll
            for (int r = 0; r < 4; ++r) {
                const int gr = d0 + row_l + m * 16 + r;
                const int gc = e0 + col_l + n * 16;
                const float e = acc[m][n][r] * inv;
                const unsigned short h = f2b(e);
                const unsigned short l = f2b(e - b2f(h));
                const size_t o = mb + (size_t)gr * DD + gc;
                Eh[o] = h; El[o] = l;
                if (gr == gc) ts += e;
            }
    if ((tc >> 1) == tr) {               // diagonal-overlap tile: reduce trace
        red[t] = ts;
        __syncthreads();
        for (int s2 = 128; s2 > 0; s2 >>= 1) {
            if (t < s2) red[t] += red[t + s2];
            __syncthreads();
        }
        if (t == 0) atomicAdd(&s_out[bb], red[0]);
    }
}

// ------- finish: column start + NPI matvecs (no renorm; lambda1 ~ 1) --------
// matrix arrives as bf16 hi/lo pair; reconstruct fp32 as hi+lo (exact to 2^-18)
__global__ __launch_bounds__(256, 2) void finish_kernel(const unsigned short* __restrict__ Dh,
                                                        const unsigned short* __restrict__ Dl,
                                                        float* __restrict__ out) {
    const int b = blockIdx.x, t = threadIdx.x;
    const size_t mb = (size_t)b * DDSQ;
    __shared__ float vs[DD];
    __shared__ float red[DD];
    __shared__ int   ridx[DD];
    red[t] = b2f(Dh[mb + (size_t)t * DD + t]) + b2f(Dl[mb + (size_t)t * DD + t]);
    ridx[t] = t;
    __syncthreads();
    for (int s = 128; s > 0; s >>= 1) {
        if (t < s && red[t + s] > red[t]) { red[t] = red[t + s]; ridx[t] = ridx[t + s]; }
        __syncthreads();
    }
    const int jmax0 = ridx[0];
    __syncthreads();
    float v = b2f(Dh[mb + (size_t)jmax0 * DD + t]) + b2f(Dl[mb + (size_t)jmax0 * DD + t]);
    for (int it = 0; it < NPI; ++it) {
        vs[t] = v;
        __syncthreads();
        float a = 0.f;
        const unsigned short* rh = Dh + mb + (size_t)t * DD;
        const unsigned short* rl = Dl + mb + (size_t)t * DD;
#pragma unroll 4
        for (int j = 0; j < DD; j += 8) {
            const us8 h8 = *(const us8*)&rh[j];
            const us8 l8 = *(const us8*)&rl[j];
            a = fmaf(b2f(h8[0]) + b2f(l8[0]), vs[j + 0], a);
            a = fmaf(b2f(h8[1]) + b2f(l8[1]), vs[j + 1], a);
            a = fmaf(b2f(h8[2]) + b2f(l8[2]), vs[j + 2], a);
            a = fmaf(b2f(h8[3]) + b2f(l8[3]), vs[j + 3], a);
            a = fmaf(b2f(h8[4]) + b2f(l8[4]), vs[j + 4], a);
            a = fmaf(b2f(h8[5]) + b2f(l8[5]), vs[j + 5], a);
            a = fmaf(b2f(h8[6]) + b2f(l8[6]), vs[j + 6], a);
            a = fmaf(b2f(h8[7]) + b2f(l8[7]), vs[j + 7], a);
        }
        __syncthreads();
        v = a;
    }
    vs[t] = v;
    red[t] = v * v;
    __syncthreads();
    for (int s = 128; s > 0; s >>= 1) {
        if (t < s) red[t] += red[t + s];
        __syncthreads();
    }
    const float nrm = sqrtf(red[0]);
    __syncthreads();
    red[t] = fabsf(v);
    ridx[t] = t;
    __syncthreads();
    for (int s = 128; s > 0; s >>= 1) {
        if (t < s && red[t + s] > red[t]) { red[t] = red[t + s]; ridx[t] = ridx[t + s]; }
        __syncthreads();
    }
    const float sgn = (vs[ridx[0]] < 0.f) ? -1.f : 1.f;
    out[(size_t)b * DD + t] = sgn * v / nrm;
}

extern "C" void kernel_launch(void* const* d_in, const int* in_sizes, int n_in,
                              void* d_out, int out_size, void* d_ws, size_t ws_size,
                              hipStream_t stream) {
    const float* caps = (const float*)d_in[0];   // (64, 2048, 16)
    const float* W    = (const float*)d_in[1];   // (2048, 16, 256)
    float* out = (float*)d_out;                  // (64, 256)
    float* ws  = (float*)d_ws;

    // layout: U = 8*PB @0 | A0 @8PB | A1 @9PB | Sc @10PB  (~168 MB)
    // bf16 hi/lo ping-pong (X @0, Y @PB) overlays dead U after c_kernel
    float* U  = ws;
    float* A0 = ws + (size_t)8 * PB;
    float* A1 = ws + (size_t)9 * PB;
    float* Sc = ws + (size_t)10 * PB;
    unsigned short* Xh = (unsigned short*)ws;
    unsigned short* Xl = Xh + (size_t)NB * DDSQ;
    unsigned short* Yh = (unsigned short*)(ws + PB);
    unsigned short* Yl = Yh + (size_t)NB * DDSQ;

    hipMemsetAsync(Sc, 0, 2048 * sizeof(float), stream);

    u_kernel<<<dim3(IC, 4), 256, 0, stream>>>(caps, W, U);
    c_kernel<<<1024, 256, 0, stream>>>(U, A0, A1, Sc);

    // first squaring folds A0+A1 (fp32) -> X (bf16 hi/lo); then 10 bf16 squarings
    sqm_kernel<true><<<512, 256, 0, stream>>>(A0, A1, nullptr, nullptr, Xh, Xl, Sc, Sc + 64);
    unsigned short* ph = Xh; unsigned short* pl = Xl;
    unsigned short* qh = Yh; unsigned short* ql = Yl;
    for (int it = 1; it < NSQ; ++it) {
        sqm_kernel<false><<<512, 256, 0, stream>>>(nullptr, nullptr, ph, pl, qh, ql,
                                                   Sc + it * 64, Sc + (it + 1) * 64);
        unsigned short* th = ph; ph = qh; qh = th;
        unsigned short* tl = pl; pl = ql; ql = tl;
    }

    finish_kernel<<<NB, 256, 0, stream>>>(ph, pl, out);   // NSQ odd -> final in X
}

// Round 3
// 545.723 us; speedup vs baseline: 1.4167x; 1.2231x over previous
//
#include <hip/hip_runtime.h>

#define NB  64
#define IC  2048
#define ID  16
#define DD  256
#define DDSQ 65536
#define PB  (DDSQ * NB)       // 4,194,304 floats = one full-batch fp32 matrix buffer
#define NSQ 11                // matrix squarings
#define NPI 7                 // finish matvecs: exponent 2^11 * 8 = 16384

typedef __attribute__((ext_vector_type(8))) short          s16x8;  // 8 bf16 (4 VGPRs) MFMA frag
typedef __attribute__((ext_vector_type(4))) float          f32x4;  // MFMA acc
typedef __attribute__((ext_vector_type(4))) unsigned short us4;
typedef __attribute__((ext_vector_type(8))) unsigned short us8;

// fp32 -> bf16 (RNE) and back, via raw bits
__device__ __forceinline__ unsigned short f2b(float f) {
    union { float f; unsigned u; } c; c.f = f;
    const unsigned u = c.u + 0x7FFFu + ((c.u >> 16) & 1u);
    return (unsigned short)(u >> 16);
}
__device__ __forceinline__ float b2f(unsigned short h) {
    union { unsigned u; float f; } c; c.u = ((unsigned)h) << 16;
    return c.f;
}
// fp32 -> packed (hi bf16 << 16) | (lo bf16): 2-term split in one u32
__device__ __forceinline__ unsigned f2pk(float f) {
    const unsigned short h = f2b(f);
    const unsigned short l = f2b(f - b2f(h));
    return ((unsigned)h << 16) | (unsigned)l;
}

#define ADDF4(a, b) { (a).x += (b).x; (a).y += (b).y; (a).z += (b).z; (a).w += (b).w; }

// ---------------- stage 1: u[b,c,:] = x[b,c,:] @ W_c (16 batches/block) -----
// output: PACKED u32 per element: (bf16_hi << 16) | bf16_lo  (same bytes as fp32)
__global__ __launch_bounds__(256, 4) void u_kernel(const float* __restrict__ caps,
                                                   const float* __restrict__ W,
                                                   unsigned* __restrict__ U) {
    const int c  = blockIdx.x;
    const int b0 = blockIdx.y * 16;
    const int t  = threadIdx.x;
    __shared__ float xsT[ID][16];        // [dim][batch]
    if (t < 64) {
        const int b = t >> 2, q = (t & 3) * 4;
        const float4 x4 = *(const float4*)&caps[((size_t)(b0 + b) * IC + c) * ID + q];
        xsT[q + 0][b] = x4.x; xsT[q + 1][b] = x4.y;
        xsT[q + 2][b] = x4.z; xsT[q + 3][b] = x4.w;
    }
    __syncthreads();
    float a0 = 0.f, a1 = 0.f, a2 = 0.f, a3 = 0.f, a4 = 0.f, a5 = 0.f, a6 = 0.f, a7 = 0.f;
    float a8 = 0.f, a9 = 0.f, a10 = 0.f, a11 = 0.f, a12 = 0.f, a13 = 0.f, a14 = 0.f, a15 = 0.f;
#pragma unroll
    for (int i = 0; i < ID; ++i) {
        const float wi = W[((size_t)c * ID + i) * DD + t];    // coalesced over t
        const float4 x0 = *(const float4*)&xsT[i][0];
        const float4 x1 = *(const float4*)&xsT[i][4];
        const float4 x2 = *(const float4*)&xsT[i][8];
        const float4 x3 = *(const float4*)&xsT[i][12];
        a0  = fmaf(x0.x, wi, a0 );  a1  = fmaf(x0.y, wi, a1 );
        a2  = fmaf(x0.z, wi, a2 );  a3  = fmaf(x0.w, wi, a3 );
        a4  = fmaf(x1.x, wi, a4 );  a5  = fmaf(x1.y, wi, a5 );
        a6  = fmaf(x1.z, wi, a6 );  a7  = fmaf(x1.w, wi, a7 );
        a8  = fmaf(x2.x, wi, a8 );  a9  = fmaf(x2.y, wi, a9 );
        a10 = fmaf(x2.z, wi, a10);  a11 = fmaf(x2.w, wi, a11);
        a12 = fmaf(x3.x, wi, a12);  a13 = fmaf(x3.y, wi, a13);
        a14 = fmaf(x3.z, wi, a14);  a15 = fmaf(x3.w, wi, a15);
    }
    U[((size_t)(b0 +  0) * IC + c) * DD + t] = f2pk(a0);
    U[((size_t)(b0 +  1) * IC + c) * DD + t] = f2pk(a1);
    U[((size_t)(b0 +  2) * IC + c) * DD + t] = f2pk(a2);
    U[((size_t)(b0 +  3) * IC + c) * DD + t] = f2pk(a3);
    U[((size_t)(b0 +  4) * IC + c) * DD + t] = f2pk(a4);
    U[((size_t)(b0 +  5) * IC + c) * DD + t] = f2pk(a5);
    U[((size_t)(b0 +  6) * IC + c) * DD + t] = f2pk(a6);
    U[((size_t)(b0 +  7) * IC + c) * DD + t] = f2pk(a7);
    U[((size_t)(b0 +  8) * IC + c) * DD + t] = f2pk(a8);
    U[((size_t)(b0 +  9) * IC + c) * DD + t] = f2pk(a9);
    U[((size_t)(b0 + 10) * IC + c) * DD + t] = f2pk(a10);
    U[((size_t)(b0 + 11) * IC + c) * DD + t] = f2pk(a11);
    U[((size_t)(b0 + 12) * IC + c) * DD + t] = f2pk(a12);
    U[((size_t)(b0 + 13) * IC + c) * DD + t] = f2pk(a13);
    U[((size_t)(b0 + 14) * IC + c) * DD + t] = f2pk(a14);
    U[((size_t)(b0 + 15) * IC + c) * DD + t] = f2pk(a15);
}

// ---- stage 2: partial C = U^T U via bf16-split MFMA, 128x64 tile -----------
// Register transpose staging: per lane, 4 coalesced dword loads from 4
// consecutive c-rows at its d-column -> lane holds a k-quad -> one us4 LDS
// write into k-inner tiles Ah/Al[d][k], Bh/Bl[e][k]. Lane->(row-octet, quad)
// map spreads each write instr uniformly over all 32 banks (4/bank floor).
// id: low6 = batch; tk = id>>6: tile = tk>>1 (2x4 of 128x64), kch = tk&1
__global__ __launch_bounds__(256, 2)
void cm_kernel(const unsigned* __restrict__ Up,
               float* __restrict__ P0, float* __restrict__ P1,
               float* __restrict__ Sc) {
    const int id   = blockIdx.x;
    const int bb   = id & 63;
    const int tk   = id >> 6;            // 0..15
    const int tile = tk >> 1, kch = tk & 1;
    const int tr = tile >> 2, tc = tile & 3;
    const int d0 = tr * 128, e0 = tc * 64;
    const int t    = threadIdx.x;
    const int lane = t & 63, wid = t >> 6;
    const int wm = wid >> 1, wn = wid & 1;            // 2x2 wave grid
    const int fr = lane & 15, kg = lane >> 4;         // frag row, k-group
    const int sl8 = lane & 7, qg = lane >> 3;         // staging: row-in-octet, k-quad

    __shared__ unsigned short Ah[128][40];   // [d][k], pitch 40 shorts (80 B)
    __shared__ unsigned short Al[128][40];
    __shared__ unsigned short Bh[64][40];    // [e][k]
    __shared__ unsigned short Bl[64][40];
    __shared__ float red[256];

    f32x4 acc[4][2] = {};
    const unsigned* Ub = Up + (size_t)bb * IC * DD;
    const int k0 = kch * (IC / 2);

    for (int kb = k0; kb < k0 + IC / 2; kb += 32) {
        // -- gather loads (register transpose): instr lanes = 8 c-rows x 8 d --
        unsigned va[4][4], vb[2][4];
#pragma unroll
        for (int s = 0; s < 4; ++s) {
            const int row = wid * 8 + sl8 + 32 * s;       // d-local 0..127
#pragma unroll
            for (int j = 0; j < 4; ++j)
                va[s][j] = Ub[(size_t)(kb + 4 * qg + j) * DD + d0 + row];
        }
#pragma unroll
        for (int s = 0; s < 2; ++s) {
            const int row = wid * 8 + sl8 + 32 * s;       // e-local 0..63
#pragma unroll
            for (int j = 0; j < 4; ++j)
                vb[s][j] = Ub[(size_t)(kb + 4 * qg + j) * DD + e0 + row];
        }
        __syncthreads();
        // -- unpack + k-inner LDS writes (us4 = one k-quad) --
#pragma unroll
        for (int s = 0; s < 4; ++s) {
            const int row = wid * 8 + sl8 + 32 * s;
            us4 h, l;
            h[0] = (unsigned short)(va[s][0] >> 16); l[0] = (unsigned short)(va[s][0] & 0xFFFFu);
            h[1] = (unsigned short)(va[s][1] >> 16); l[1] = (unsigned short)(va[s][1] & 0xFFFFu);
            h[2] = (unsigned short)(va[s][2] >> 16); l[2] = (unsigned short)(va[s][2] & 0xFFFFu);
            h[3] = (unsigned short)(va[s][3] >> 16); l[3] = (unsigned short)(va[s][3] & 0xFFFFu);
            *(us4*)&Ah[row][4 * qg] = h;
            *(us4*)&Al[row][4 * qg] = l;
        }
#pragma unroll
        for (int s = 0; s < 2; ++s) {
            const int row = wid * 8 + sl8 + 32 * s;
            us4 h, l;
            h[0] = (unsigned short)(vb[s][0] >> 16); l[0] = (unsigned short)(vb[s][0] & 0xFFFFu);
            h[1] = (unsigned short)(vb[s][1] >> 16); l[1] = (unsigned short)(vb[s][1] & 0xFFFFu);
            h[2] = (unsigned short)(vb[s][2] >> 16); l[2] = (unsigned short)(vb[s][2] & 0xFFFFu);
            h[3] = (unsigned short)(vb[s][3] >> 16); l[3] = (unsigned short)(vb[s][3] & 0xFFFFu);
            *(us4*)&Bh[row][4 * qg] = h;
            *(us4*)&Bl[row][4 * qg] = l;
        }
        __syncthreads();
        // -- fragments + 3-term MFMA --
        s16x8 ah[4], al[4], bh[2], bl[2];
#pragma unroll
        for (int m = 0; m < 4; ++m) {
            const int r = wm * 64 + m * 16 + fr;
            ah[m] = *(const s16x8*)&Ah[r][kg * 8];
            al[m] = *(const s16x8*)&Al[r][kg * 8];
        }
#pragma unroll
        for (int n = 0; n < 2; ++n) {
            const int r = wn * 32 + n * 16 + fr;
            bh[n] = *(const s16x8*)&Bh[r][kg * 8];
            bl[n] = *(const s16x8*)&Bl[r][kg * 8];
        }
#pragma unroll
        for (int m = 0; m < 4; ++m)
#pragma unroll
            for (int n = 0; n < 2; ++n) {
                acc[m][n] = __builtin_amdgcn_mfma_f32_16x16x32_bf16(ah[m], bh[n], acc[m][n], 0, 0, 0);
                acc[m][n] = __builtin_amdgcn_mfma_f32_16x16x32_bf16(ah[m], bl[n], acc[m][n], 0, 0, 0);
                acc[m][n] = __builtin_amdgcn_mfma_f32_16x16x32_bf16(al[m], bh[n], acc[m][n], 0, 0, 0);
            }
    }

    // -- epilogue: fp32 partial store + fused trace --
    float* Pb = (kch ? P1 : P0) + (size_t)bb * DDSQ;
    float ts = 0.f;
    const int row_l = (lane >> 4) * 4;
#pragma unroll
    for (int m = 0; m < 4; ++m)
#pragma unroll
        for (int n = 0; n < 2; ++n)
#pragma unroll
            for (int r = 0; r < 4; ++r) {
                const int gr = d0 + wm * 64 + m * 16 + row_l + r;
                const int gc = e0 + wn * 32 + n * 16 + fr;
                Pb[(size_t)gr * DD + gc] = acc[m][n][r];
                if (gr == gc) ts += acc[m][n][r];
            }
    if ((tc >> 1) == tr) {               // diagonal-overlap tile: reduce trace
        red[t] = ts;
        __syncthreads();
        for (int s2 = 128; s2 > 0; s2 >>= 1) {
            if (t < s2) red[t] += red[t + s2];
            __syncthreads();
        }
        if (t == 0) atomicAdd(&Sc[bb], red[0]);
    }
}

// ---- E = (D/s)^2 via bf16-split MFMA, 128x64 tile, 4 waves (2x2) -----------
// D symmetric => B-panel rows e0..e0+63 of D give B[k][j] directly in [j][k]
// FIRST: inputs are fp32 P0+P1 (folded, converted in staging); else bf16 hi/lo.
template<bool FIRST>
__global__ __launch_bounds__(256, 2)
void sqm_kernel(const float* __restrict__ F0, const float* __restrict__ F1,
                const unsigned short* __restrict__ Dh, const unsigned short* __restrict__ Dl,
                unsigned short* __restrict__ Eh, unsigned short* __restrict__ El,
                const float* __restrict__ s_in, float* __restrict__ s_out) {
    const int id   = blockIdx.x;          // 512 = 64 batches x 8 tiles
    const int bb   = id & 63;
    const int tile = id >> 6;             // 0..7
    const int tr = tile >> 2, tc = tile & 3;
    const int d0 = tr * 128, e0 = tc * 64;
    const int t    = threadIdx.x;
    const int lane = t & 63, wid = t >> 6;
    const int wm = wid >> 1, wn = wid & 1;            // 2x2 wave grid
    const int fr = lane & 15, kg = lane >> 4;          // frag row/col, k-group

    __shared__ unsigned short Ah[128][40];
    __shared__ unsigned short Al[128][40];
    __shared__ unsigned short Bh[64][40];
    __shared__ unsigned short Bl[64][40];
    __shared__ float red[256];

    f32x4 acc[4][2] = {};
    const size_t mb = (size_t)bb * DDSQ;
    const float s   = s_in[bb];
    const float inv = 1.f / (s * s);

    for (int kb = 0; kb < DD; kb += 32) {
        if constexpr (FIRST) {
            // fp32 staging: fold P0+P1, convert to hi/lo during LDS write
            float4 va[4], vb[2];
#pragma unroll
            for (int i = 0; i < 4; ++i) {
                const int slot = t + i * 256;              // 0..1023
                const int row = slot >> 3, q = slot & 7;   // 8 float4 per 32-f32 row
                const size_t g = mb + (size_t)(d0 + row) * DD + kb + q * 4;
                float4 x = *(const float4*)&F0[g];
                const float4 y = *(const float4*)&F1[g];
                ADDF4(x, y);
                va[i] = x;
            }
#pragma unroll
            for (int i = 0; i < 2; ++i) {
                const int slot = t + i * 256;              // 0..511
                const int row = slot >> 3, q = slot & 7;
                const size_t g = mb + (size_t)(e0 + row) * DD + kb + q * 4;
                float4 x = *(const float4*)&F0[g];
                const float4 y = *(const float4*)&F1[g];
                ADDF4(x, y);
                vb[i] = x;
            }
            __syncthreads();
#pragma unroll
            for (int i = 0; i < 4; ++i) {
                const int slot = t + i * 256;
                const int row = slot >> 3, q = slot & 7;
                us4 h, l;
                h.x = f2b(va[i].x); l.x = f2b(va[i].x - b2f(h.x));
                h.y = f2b(va[i].y); l.y = f2b(va[i].y - b2f(h.y));
                h.z = f2b(va[i].z); l.z = f2b(va[i].z - b2f(h.z));
                h.w = f2b(va[i].w); l.w = f2b(va[i].w - b2f(h.w));
                *(us4*)&Ah[row][q * 4] = h;
                *(us4*)&Al[row][q * 4] = l;
            }
#pragma unroll
            for (int i = 0; i < 2; ++i) {
                const int slot = t + i * 256;
                const int row = slot >> 3, q = slot & 7;
                us4 h, l;
                h.x = f2b(vb[i].x); l.x = f2b(vb[i].x - b2f(h.x));
                h.y = f2b(vb[i].y); l.y = f2b(vb[i].y - b2f(h.y));
                h.z = f2b(vb[i].z); l.z = f2b(vb[i].z - b2f(h.z));
                h.w = f2b(vb[i].w); l.w = f2b(vb[i].w - b2f(h.w));
                *(us4*)&Bh[row][q * 4] = h;
                *(us4*)&Bl[row][q * 4] = l;
            }
            __syncthreads();
        } else {
            // bf16 staging: straight int4 copies, no conversion
            int4 rah[2], ral[2], rbh, rbl;
#pragma unroll
            for (int i = 0; i < 2; ++i) {
                const int slot = t + i * 256;              // 0..511
                const int row = slot >> 2, q = slot & 3;   // 4 int4 per 32-bf16 row
                const size_t g = mb + (size_t)(d0 + row) * DD + kb + q * 8;
                rah[i] = *(const int4*)&Dh[g];
                ral[i] = *(const int4*)&Dl[g];
            }
            {
                const int row = t >> 2, q = t & 3;
                const size_t g = mb + (size_t)(e0 + row) * DD + kb + q * 8;
                rbh = *(const int4*)&Dh[g];
                rbl = *(const int4*)&Dl[g];
            }
            __syncthreads();
#pragma unroll
            for (int i = 0; i < 2; ++i) {
                const int slot = t + i * 256;
                const int row = slot >> 2, q = slot & 3;
                *(int4*)&Ah[row][q * 8] = rah[i];
                *(int4*)&Al[row][q * 8] = ral[i];
            }
            {
                const int row = t >> 2, q = t & 3;
                *(int4*)&Bh[row][q * 8] = rbh;
                *(int4*)&Bl[row][q * 8] = rbl;
            }
            __syncthreads();
        }

        // fragments: A[m=fr][k=kg*8+j] / B[k=kg*8+j][fr] — identical addressing
        s16x8 ah[4], al[4], bh[2], bl[2];
#pragma unroll
        for (int m = 0; m < 4; ++m) {
            const int r = wm * 64 + m * 16 + fr;
            ah[m] = *(const s16x8*)&Ah[r][kg * 8];
            al[m] = *(const s16x8*)&Al[r][kg * 8];
        }
#pragma unroll
        for (int n = 0; n < 2; ++n) {
            const int r = wn * 32 + n * 16 + fr;
            bh[n] = *(const s16x8*)&Bh[r][kg * 8];
            bl[n] = *(const s16x8*)&Bl[r][kg * 8];
        }
#pragma unroll
        for (int m = 0; m < 4; ++m)
#pragma unroll
            for (int n = 0; n < 2; ++n) {
                acc[m][n] = __builtin_amdgcn_mfma_f32_16x16x32_bf16(ah[m], bh[n], acc[m][n], 0, 0, 0);
                acc[m][n] = __builtin_amdgcn_mfma_f32_16x16x32_bf16(ah[m], bl[n], acc[m][n], 0, 0, 0);
                acc[m][n] = __builtin_amdgcn_mfma_f32_16x16x32_bf16(al[m], bh[n], acc[m][n], 0, 0, 0);
            }
    }

    // epilogue: scale, fused trace, split to hi/lo bf16
    float ts = 0.f;
    const int row_l = wm * 64 + (lane >> 4) * 4;     // + m*16 + r
    const int col_l = wn * 32 + fr;                  // + n*16
#pragma unroll
    for (int m = 0; m < 4; ++m)
#pragma unroll
        for (int n = 0; n < 2; ++n)
#pragma unroll
            for (int r = 0; r < 4; ++r) {
                const int gr = d0 + row_l + m * 16 + r;
                const int gc = e0 + col_l + n * 16;
                const float e = acc[m][n][r] * inv;
                const unsigned short h = f2b(e);
                const unsigned short l = f2b(e - b2f(h));
                const size_t o = mb + (size_t)gr * DD + gc;
                Eh[o] = h; El[o] = l;
                if (gr == gc) ts += e;
            }
    if ((tc >> 1) == tr) {               // diagonal-overlap tile: reduce trace
        red[t] = ts;
        __syncthreads();
        for (int s2 = 128; s2 > 0; s2 >>= 1) {
            if (t < s2) red[t] += red[t + s2];
            __syncthreads();
        }
        if (t == 0) atomicAdd(&s_out[bb], red[0]);
    }
}

// ------- finish: column start + NPI matvecs (no renorm; lambda1 ~ 1) --------
__global__ __launch_bounds__(256, 2) void finish_kernel(const unsigned short* __restrict__ Dh,
                                                        const unsigned short* __restrict__ Dl,
                                                        float* __restrict__ out) {
    const int b = blockIdx.x, t = threadIdx.x;
    const size_t mb = (size_t)b * DDSQ;
    __shared__ float vs[DD];
    __shared__ float red[DD];
    __shared__ int   ridx[DD];
    red[t] = b2f(Dh[mb + (size_t)t * DD + t]) + b2f(Dl[mb + (size_t)t * DD + t]);
    ridx[t] = t;
    __syncthreads();
    for (int s = 128; s > 0; s >>= 1) {
        if (t < s && red[t + s] > red[t]) { red[t] = red[t + s]; ridx[t] = ridx[t + s]; }
        __syncthreads();
    }
    const int jmax0 = ridx[0];
    __syncthreads();
    float v = b2f(Dh[mb + (size_t)jmax0 * DD + t]) + b2f(Dl[mb + (size_t)jmax0 * DD + t]);
    for (int it = 0; it < NPI; ++it) {
        vs[t] = v;
        __syncthreads();
        float a = 0.f;
        const unsigned short* rh = Dh + mb + (size_t)t * DD;
        const unsigned short* rl = Dl + mb + (size_t)t * DD;
#pragma unroll 4
        for (int j = 0; j < DD; j += 8) {
            const us8 h8 = *(const us8*)&rh[j];
            const us8 l8 = *(const us8*)&rl[j];
            a = fmaf(b2f(h8[0]) + b2f(l8[0]), vs[j + 0], a);
            a = fmaf(b2f(h8[1]) + b2f(l8[1]), vs[j + 1], a);
            a = fmaf(b2f(h8[2]) + b2f(l8[2]), vs[j + 2], a);
            a = fmaf(b2f(h8[3]) + b2f(l8[3]), vs[j + 3], a);
            a = fmaf(b2f(h8[4]) + b2f(l8[4]), vs[j + 4], a);
            a = fmaf(b2f(h8[5]) + b2f(l8[5]), vs[j + 5], a);
            a = fmaf(b2f(h8[6]) + b2f(l8[6]), vs[j + 6], a);
            a = fmaf(b2f(h8[7]) + b2f(l8[7]), vs[j + 7], a);
        }
        __syncthreads();
        v = a;
    }
    vs[t] = v;
    red[t] = v * v;
    __syncthreads();
    for (int s = 128; s > 0; s >>= 1) {
        if (t < s) red[t] += red[t + s];
        __syncthreads();
    }
    const float nrm = sqrtf(red[0]);
    __syncthreads();
    red[t] = fabsf(v);
    ridx[t] = t;
    __syncthreads();
    for (int s = 128; s > 0; s >>= 1) {
        if (t < s && red[t + s] > red[t]) { red[t] = red[t + s]; ridx[t] = ridx[t + s]; }
        __syncthreads();
    }
    const float sgn = (vs[ridx[0]] < 0.f) ? -1.f : 1.f;
    out[(size_t)b * DD + t] = sgn * v / nrm;
}

extern "C" void kernel_launch(void* const* d_in, const int* in_sizes, int n_in,
                              void* d_out, int out_size, void* d_ws, size_t ws_size,
                              hipStream_t stream) {
    const float* caps = (const float*)d_in[0];   // (64, 2048, 16)
    const float* W    = (const float*)d_in[1];   // (2048, 16, 256)
    float* out = (float*)d_out;                  // (64, 256)
    float* ws  = (float*)d_ws;

    // layout: U' packed = 8*PB @0 | A0 @8PB | A1 @9PB | Sc @10PB  (~160 MB)
    // bf16 hi/lo ping-pong (X @0, Y @PB) overlays dead U' after cm_kernel
    unsigned* Up = (unsigned*)ws;
    float* A0 = ws + (size_t)8 * PB;
    float* A1 = ws + (size_t)9 * PB;
    float* Sc = ws + (size_t)10 * PB;
    unsigned short* Xh = (unsigned short*)ws;
    unsigned short* Xl = Xh + (size_t)NB * DDSQ;
    unsigned short* Yh = (unsigned short*)(ws + PB);
    unsigned short* Yl = Yh + (size_t)NB * DDSQ;

    hipMemsetAsync(Sc, 0, 2048 * sizeof(float), stream);

    u_kernel<<<dim3(IC, 4), 256, 0, stream>>>(caps, W, Up);
    cm_kernel<<<1024, 256, 0, stream>>>(Up, A0, A1, Sc);

    // first squaring folds A0+A1 (fp32) -> X (bf16 hi/lo); then 10 bf16 squarings
    sqm_kernel<true><<<512, 256, 0, stream>>>(A0, A1, nullptr, nullptr, Xh, Xl, Sc, Sc + 64);
    unsigned short* ph = Xh; unsigned short* pl = Xl;
    unsigned short* qh = Yh; unsigned short* ql = Yl;
    for (int it = 1; it < NSQ; ++it) {
        sqm_kernel<false><<<512, 256, 0, stream>>>(nullptr, nullptr, ph, pl, qh, ql,
                                                   Sc + it * 64, Sc + (it + 1) * 64);
        unsigned short* th = ph; ph = qh; qh = th;
        unsigned short* tl = pl; pl = ql; ql = tl;
    }

    finish_kernel<<<NB, 256, 0, stream>>>(ph, pl, out);   // NSQ odd -> final in X
}

// Round 6
// 525.455 us; speedup vs baseline: 1.4713x; 1.0386x over previous
//
#include <hip/hip_runtime.h>

#define NB  64
#define IC  2048
#define ID  16
#define DD  256
#define DDSQ 65536
#define PB  (DDSQ * NB)       // 4,194,304 floats = one full-batch fp32-sized buffer
#define NSQ 11                // matrix squarings
#define NPI 7                 // finish matvecs: exponent 2^11 * 8 = 16384

typedef __attribute__((ext_vector_type(8))) short          s16x8;  // 8 bf16 (4 VGPRs) MFMA frag
typedef __attribute__((ext_vector_type(4))) float          f32x4;  // MFMA acc
typedef __attribute__((ext_vector_type(4))) unsigned short us4;
typedef __attribute__((ext_vector_type(8))) unsigned short us8;

// fp32 -> bf16 (RNE) and back, via raw bits
__device__ __forceinline__ unsigned short f2b(float f) {
    union { float f; unsigned u; } c; c.f = f;
    const unsigned u = c.u + 0x7FFFu + ((c.u >> 16) & 1u);
    return (unsigned short)(u >> 16);
}
__device__ __forceinline__ float b2f(unsigned short h) {
    union { unsigned u; float f; } c; c.u = ((unsigned)h) << 16;
    return c.f;
}
// fp32 -> packed (hi bf16 << 16) | (lo bf16): 2-term split in one u32
__device__ __forceinline__ unsigned f2pk(float f) {
    const unsigned short h = f2b(f);
    const unsigned short l = f2b(f - b2f(h));
    return ((unsigned)h << 16) | (unsigned)l;
}

// ---------------- stage 1: u[b,c,:] = x[b,c,:] @ W_c (16 batches/block) -----
// output: PACKED u32 per element: (bf16_hi << 16) | bf16_lo
__global__ __launch_bounds__(256, 4) void u_kernel(const float* __restrict__ caps,
                                                   const float* __restrict__ W,
                                                   unsigned* __restrict__ U) {
    const int c  = blockIdx.x;
    const int b0 = blockIdx.y * 16;
    const int t  = threadIdx.x;
    __shared__ float xsT[ID][16];        // [dim][batch]
    if (t < 64) {
        const int b = t >> 2, q = (t & 3) * 4;
        const float4 x4 = *(const float4*)&caps[((size_t)(b0 + b) * IC + c) * ID + q];
        xsT[q + 0][b] = x4.x; xsT[q + 1][b] = x4.y;
        xsT[q + 2][b] = x4.z; xsT[q + 3][b] = x4.w;
    }
    __syncthreads();
    float a0 = 0.f, a1 = 0.f, a2 = 0.f, a3 = 0.f, a4 = 0.f, a5 = 0.f, a6 = 0.f, a7 = 0.f;
    float a8 = 0.f, a9 = 0.f, a10 = 0.f, a11 = 0.f, a12 = 0.f, a13 = 0.f, a14 = 0.f, a15 = 0.f;
#pragma unroll
    for (int i = 0; i < ID; ++i) {
        const float wi = W[((size_t)c * ID + i) * DD + t];    // coalesced over t
        const float4 x0 = *(const float4*)&xsT[i][0];
        const float4 x1 = *(const float4*)&xsT[i][4];
        const float4 x2 = *(const float4*)&xsT[i][8];
        const float4 x3 = *(const float4*)&xsT[i][12];
        a0  = fmaf(x0.x, wi, a0 );  a1  = fmaf(x0.y, wi, a1 );
        a2  = fmaf(x0.z, wi, a2 );  a3  = fmaf(x0.w, wi, a3 );
        a4  = fmaf(x1.x, wi, a4 );  a5  = fmaf(x1.y, wi, a5 );
        a6  = fmaf(x1.z, wi, a6 );  a7  = fmaf(x1.w, wi, a7 );
        a8  = fmaf(x2.x, wi, a8 );  a9  = fmaf(x2.y, wi, a9 );
        a10 = fmaf(x2.z, wi, a10);  a11 = fmaf(x2.w, wi, a11);
        a12 = fmaf(x3.x, wi, a12);  a13 = fmaf(x3.y, wi, a13);
        a14 = fmaf(x3.z, wi, a14);  a15 = fmaf(x3.w, wi, a15);
    }
    U[((size_t)(b0 +  0) * IC + c) * DD + t] = f2pk(a0);
    U[((size_t)(b0 +  1) * IC + c) * DD + t] = f2pk(a1);
    U[((size_t)(b0 +  2) * IC + c) * DD + t] = f2pk(a2);
    U[((size_t)(b0 +  3) * IC + c) * DD + t] = f2pk(a3);
    U[((size_t)(b0 +  4) * IC + c) * DD + t] = f2pk(a4);
    U[((size_t)(b0 +  5) * IC + c) * DD + t] = f2pk(a5);
    U[((size_t)(b0 +  6) * IC + c) * DD + t] = f2pk(a6);
    U[((size_t)(b0 +  7) * IC + c) * DD + t] = f2pk(a7);
    U[((size_t)(b0 +  8) * IC + c) * DD + t] = f2pk(a8);
    U[((size_t)(b0 +  9) * IC + c) * DD + t] = f2pk(a9);
    U[((size_t)(b0 + 10) * IC + c) * DD + t] = f2pk(a10);
    U[((size_t)(b0 + 11) * IC + c) * DD + t] = f2pk(a11);
    U[((size_t)(b0 + 12) * IC + c) * DD + t] = f2pk(a12);
    U[((size_t)(b0 + 13) * IC + c) * DD + t] = f2pk(a13);
    U[((size_t)(b0 + 14) * IC + c) * DD + t] = f2pk(a14);
    U[((size_t)(b0 + 15) * IC + c) * DD + t] = f2pk(a15);
}

// ---- stage 2: C = U^T U (full K), bf16 hi/lo out + trace, 512 blocks -------
// Register-transpose staging + T14 prefetch (issue k+1 loads before MFMA k).
// (ran clean in round-4 pytest; kept as-is)
__global__ __launch_bounds__(256, 2)
void cmb_kernel(const unsigned* __restrict__ Up,
                unsigned short* __restrict__ Ch, unsigned short* __restrict__ Cl,
                float* __restrict__ Sc) {
    const int id   = blockIdx.x;
    const int bb   = id & 63;
    const int tile = id >> 6;            // 0..7 (2x4 of 128x64)
    const int tr = tile >> 2, tc = tile & 3;
    const int d0 = tr * 128, e0 = tc * 64;
    const int t    = threadIdx.x;
    const int lane = t & 63, wid = t >> 6;
    const int wm = wid >> 1, wn = wid & 1;            // 2x2 wave grid
    const int fr = lane & 15, kg = lane >> 4;         // frag row, k-group
    const int sl8 = lane & 7, qg = lane >> 3;         // staging: row-in-octet, k-quad
    const size_t mb = (size_t)bb * DDSQ;

    __shared__ unsigned short Ah[128][40];   // [d][k], pitch 40 shorts (80 B)
    __shared__ unsigned short Al[128][40];
    __shared__ unsigned short Bh[64][40];    // [e][k]
    __shared__ unsigned short Bl[64][40];
    __shared__ float red[256];

    const f32x4 z4 = {0.f, 0.f, 0.f, 0.f};
    f32x4 acc[4][2];
#pragma unroll
    for (int m = 0; m < 4; ++m)
#pragma unroll
        for (int n = 0; n < 2; ++n) acc[m][n] = z4;

    const unsigned* Ub = Up + (size_t)bb * IC * DD;
    unsigned va[4][4], vb[2][4];
    auto loadU = [&](int kb) {
#pragma unroll
        for (int s = 0; s < 4; ++s) {
            const int row = wid * 8 + sl8 + 32 * s;       // d-local 0..127
#pragma unroll
            for (int j = 0; j < 4; ++j)
                va[s][j] = Ub[(size_t)(kb + 4 * qg + j) * DD + d0 + row];
        }
#pragma unroll
        for (int s = 0; s < 2; ++s) {
            const int row = wid * 8 + sl8 + 32 * s;       // e-local 0..63
#pragma unroll
            for (int j = 0; j < 4; ++j)
                vb[s][j] = Ub[(size_t)(kb + 4 * qg + j) * DD + e0 + row];
        }
    };

    loadU(0);
    for (int kb = 0; kb < IC; kb += 32) {
        __syncthreads();
#pragma unroll
        for (int s = 0; s < 4; ++s) {
            const int row = wid * 8 + sl8 + 32 * s;
            us4 h, l;
#pragma unroll
            for (int j = 0; j < 4; ++j) {
                h[j] = (unsigned short)(va[s][j] >> 16);
                l[j] = (unsigned short)(va[s][j] & 0xFFFFu);
            }
            *(us4*)&Ah[row][4 * qg] = h;
            *(us4*)&Al[row][4 * qg] = l;
        }
#pragma unroll
        for (int s = 0; s < 2; ++s) {
            const int row = wid * 8 + sl8 + 32 * s;
            us4 h, l;
#pragma unroll
            for (int j = 0; j < 4; ++j) {
                h[j] = (unsigned short)(vb[s][j] >> 16);
                l[j] = (unsigned short)(vb[s][j] & 0xFFFFu);
            }
            *(us4*)&Bh[row][4 * qg] = h;
            *(us4*)&Bl[row][4 * qg] = l;
        }
        __syncthreads();
        if (kb + 32 < IC) loadU(kb + 32);     // T14: next loads fly under MFMA
        s16x8 ah[4], al[4], bh[2], bl[2];
#pragma unroll
        for (int m = 0; m < 4; ++m) {
            const int r = wm * 64 + m * 16 + fr;
            ah[m] = *(const s16x8*)&Ah[r][kg * 8];
            al[m] = *(const s16x8*)&Al[r][kg * 8];
        }
#pragma unroll
        for (int n = 0; n < 2; ++n) {
            const int r = wn * 32 + n * 16 + fr;
            bh[n] = *(const s16x8*)&Bh[r][kg * 8];
            bl[n] = *(const s16x8*)&Bl[r][kg * 8];
        }
#pragma unroll
        for (int m = 0; m < 4; ++m)
#pragma unroll
            for (int n = 0; n < 2; ++n) {
                acc[m][n] = __builtin_amdgcn_mfma_f32_16x16x32_bf16(ah[m], bh[n], acc[m][n], 0, 0, 0);
                acc[m][n] = __builtin_amdgcn_mfma_f32_16x16x32_bf16(ah[m], bl[n], acc[m][n], 0, 0, 0);
                acc[m][n] = __builtin_amdgcn_mfma_f32_16x16x32_bf16(al[m], bh[n], acc[m][n], 0, 0, 0);
            }
    }

    // epilogue: bf16 hi/lo store (UNSCALED C) + fp32 trace
    float ts = 0.f;
    const int row_l = wm * 64 + (lane >> 4) * 4;
    const int col_l = wn * 32 + fr;
#pragma unroll
    for (int m = 0; m < 4; ++m)
#pragma unroll
        for (int n = 0; n < 2; ++n)
#pragma unroll
            for (int r = 0; r < 4; ++r) {
                const int gr = d0 + row_l + m * 16 + r;
                const int gc = e0 + col_l + n * 16;
                const float e = acc[m][n][r];
                const unsigned short h = f2b(e);
                const unsigned short l = f2b(e - b2f(h));
                const size_t o = mb + (size_t)gr * DD + gc;
                Ch[o] = h; Cl[o] = l;
                if (gr == gc) ts += e;
            }
    if ((tc >> 1) == tr) {
        red[t] = ts;
        __syncthreads();
        for (int s2 = 128; s2 > 0; s2 >>= 1) {
            if (t < s2) red[t] += red[t + s2];
            __syncthreads();
        }
        if (t == 0) atomicAdd(&Sc[bb], red[0]);
    }
}

// ---- E = (D/s)^2 via bf16-split MFMA, 128x64 tile -------------------------
// EXACT round-3-proven body (loads at loop top, two barriers, NO prefetch).
// D symmetric => B-panel rows e0..e0+63 of D give B[k][j] directly in [j][k]
__global__ __launch_bounds__(256, 2)
void sqm_kernel(const unsigned short* __restrict__ Dh, const unsigned short* __restrict__ Dl,
                unsigned short* __restrict__ Eh, unsigned short* __restrict__ El,
                const float* __restrict__ s_in, float* __restrict__ s_out) {
    const int id   = blockIdx.x;          // 512 = 64 batches x 8 tiles
    const int bb   = id & 63;
    const int tile = id >> 6;             // 0..7
    const int tr = tile >> 2, tc = tile & 3;
    const int d0 = tr * 128, e0 = tc * 64;
    const int t    = threadIdx.x;
    const int lane = t & 63, wid = t >> 6;
    const int wm = wid >> 1, wn = wid & 1;
    const int fr = lane & 15, kg = lane >> 4;
    const size_t mb = (size_t)bb * DDSQ;

    __shared__ unsigned short Ah[128][40];
    __shared__ unsigned short Al[128][40];
    __shared__ unsigned short Bh[64][40];
    __shared__ unsigned short Bl[64][40];
    __shared__ float red[256];

    const f32x4 z4 = {0.f, 0.f, 0.f, 0.f};
    f32x4 acc[4][2];
#pragma unroll
    for (int m = 0; m < 4; ++m)
#pragma unroll
        for (int n = 0; n < 2; ++n) acc[m][n] = z4;

    const float s   = s_in[bb];
    const float inv = 1.f / (s * s);

    for (int kb = 0; kb < DD; kb += 32) {
        // bf16 staging: straight int4 copies (round-3 structure)
        int4 rah[2], ral[2], rbh, rbl;
#pragma unroll
        for (int i2 = 0; i2 < 2; ++i2) {
            const int slot = t + i2 * 256;              // 0..511
            const int row = slot >> 2, q = slot & 3;    // 4 int4 per 32-bf16 row
            const size_t g = mb + (size_t)(d0 + row) * DD + kb + q * 8;
            rah[i2] = *(const int4*)&Dh[g];
            ral[i2] = *(const int4*)&Dl[g];
        }
        {
            const int row = t >> 2, q = t & 3;
            const size_t g = mb + (size_t)(e0 + row) * DD + kb + q * 8;
            rbh = *(const int4*)&Dh[g];
            rbl = *(const int4*)&Dl[g];
        }
        __syncthreads();
#pragma unroll
        for (int i2 = 0; i2 < 2; ++i2) {
            const int slot = t + i2 * 256;
            const int row = slot >> 2, q = slot & 3;
            *(int4*)&Ah[row][q * 8] = rah[i2];
            *(int4*)&Al[row][q * 8] = ral[i2];
        }
        {
            const int row = t >> 2, q = t & 3;
            *(int4*)&Bh[row][q * 8] = rbh;
            *(int4*)&Bl[row][q * 8] = rbl;
        }
        __syncthreads();

        s16x8 ah[4], al[4], bh[2], bl[2];
#pragma unroll
        for (int m = 0; m < 4; ++m) {
            const int r = wm * 64 + m * 16 + fr;
            ah[m] = *(const s16x8*)&Ah[r][kg * 8];
            al[m] = *(const s16x8*)&Al[r][kg * 8];
        }
#pragma unroll
        for (int n = 0; n < 2; ++n) {
            const int r = wn * 32 + n * 16 + fr;
            bh[n] = *(const s16x8*)&Bh[r][kg * 8];
            bl[n] = *(const s16x8*)&Bl[r][kg * 8];
        }
#pragma unroll
        for (int m = 0; m < 4; ++m)
#pragma unroll
            for (int n = 0; n < 2; ++n) {
                acc[m][n] = __builtin_amdgcn_mfma_f32_16x16x32_bf16(ah[m], bh[n], acc[m][n], 0, 0, 0);
                acc[m][n] = __builtin_amdgcn_mfma_f32_16x16x32_bf16(ah[m], bl[n], acc[m][n], 0, 0, 0);
                acc[m][n] = __builtin_amdgcn_mfma_f32_16x16x32_bf16(al[m], bh[n], acc[m][n], 0, 0, 0);
            }
    }

    // epilogue: scale, trace, split to hi/lo bf16
    float ts = 0.f;
    const int row_l = wm * 64 + (lane >> 4) * 4;
    const int col_l = wn * 32 + fr;
#pragma unroll
    for (int m = 0; m < 4; ++m)
#pragma unroll
        for (int n = 0; n < 2; ++n)
#pragma unroll
            for (int r = 0; r < 4; ++r) {
                const int gr = d0 + row_l + m * 16 + r;
                const int gc = e0 + col_l + n * 16;
                const float e = acc[m][n][r] * inv;
                const unsigned short h = f2b(e);
                const unsigned short l = f2b(e - b2f(h));
                const size_t o = mb + (size_t)gr * DD + gc;
                Eh[o] = h; El[o] = l;
                if (gr == gc) ts += e;
            }
    if ((tc >> 1) == tr) {
        red[t] = ts;
        __syncthreads();
        for (int s2 = 128; s2 > 0; s2 >>= 1) {
            if (t < s2) red[t] += red[t + s2];
            __syncthreads();
        }
        if (t == 0) atomicAdd(&s_out[bb], red[0]);
    }
}

// ------- finish: column start + NPI matvecs (no renorm; lambda1 ~ 1) --------
__global__ __launch_bounds__(256, 2) void finish_kernel(const unsigned short* __restrict__ Dh,
                                                        const unsigned short* __restrict__ Dl,
                                                        float* __restrict__ out) {
    const int b = blockIdx.x, t = threadIdx.x;
    const size_t mb = (size_t)b * DDSQ;
    __shared__ float vs[DD];
    __shared__ float red[DD];
    __shared__ int   ridx[DD];
    red[t] = b2f(Dh[mb + (size_t)t * DD + t]) + b2f(Dl[mb + (size_t)t * DD + t]);
    ridx[t] = t;
    __syncthreads();
    for (int s = 128; s > 0; s >>= 1) {
        if (t < s && red[t + s] > red[t]) { red[t] = red[t + s]; ridx[t] = ridx[t + s]; }
        __syncthreads();
    }
    const int jmax0 = ridx[0];
    __syncthreads();
    float v = b2f(Dh[mb + (size_t)jmax0 * DD + t]) + b2f(Dl[mb + (size_t)jmax0 * DD + t]);
    for (int it = 0; it < NPI; ++it) {
        vs[t] = v;
        __syncthreads();
        float a = 0.f;
        const unsigned short* rh = Dh + mb + (size_t)t * DD;
        const unsigned short* rl = Dl + mb + (size_t)t * DD;
#pragma unroll 4
        for (int j = 0; j < DD; j += 8) {
            const us8 h8 = *(const us8*)&rh[j];
            const us8 l8 = *(const us8*)&rl[j];
            a = fmaf(b2f(h8[0]) + b2f(l8[0]), vs[j + 0], a);
            a = fmaf(b2f(h8[1]) + b2f(l8[1]), vs[j + 1], a);
            a = fmaf(b2f(h8[2]) + b2f(l8[2]), vs[j + 2], a);
            a = fmaf(b2f(h8[3]) + b2f(l8[3]), vs[j + 3], a);
            a = fmaf(b2f(h8[4]) + b2f(l8[4]), vs[j + 4], a);
            a = fmaf(b2f(h8[5]) + b2f(l8[5]), vs[j + 5], a);
            a = fmaf(b2f(h8[6]) + b2f(l8[6]), vs[j + 6], a);
            a = fmaf(b2f(h8[7]) + b2f(l8[7]), vs[j + 7], a);
        }
        __syncthreads();
        v = a;
    }
    vs[t] = v;
    red[t] = v * v;
    __syncthreads();
    for (int s = 128; s > 0; s >>= 1) {
        if (t < s) red[t] += red[t + s];
        __syncthreads();
    }
    const float nrm = sqrtf(red[0]);
    __syncthreads();
    red[t] = fabsf(v);
    ridx[t] = t;
    __syncthreads();
    for (int s = 128; s > 0; s >>= 1) {
        if (t < s && red[t + s] > red[t]) { red[t] = red[t + s]; ridx[t] = ridx[t + s]; }
        __syncthreads();
    }
    const float sgn = (vs[ridx[0]] < 0.f) ? -1.f : 1.f;
    out[(size_t)b * DD + t] = sgn * v / nrm;
}

extern "C" void kernel_launch(void* const* d_in, const int* in_sizes, int n_in,
                              void* d_out, int out_size, void* d_ws, size_t ws_size,
                              hipStream_t stream) {
    const float* caps = (const float*)d_in[0];   // (64, 2048, 16)
    const float* W    = (const float*)d_in[1];   // (2048, 16, 256)
    float* out = (float*)d_out;                  // (64, 256)
    float* ws  = (float*)d_ws;

    // layout: Up packed = 8*PB @0 | X @8PB | Y @9PB | Sc @10PB  (~168 MB)
    unsigned* Up = (unsigned*)ws;
    unsigned short* Xh = (unsigned short*)(ws + (size_t)8 * PB);
    unsigned short* Xl = Xh + (size_t)NB * DDSQ;
    unsigned short* Yh = (unsigned short*)(ws + (size_t)9 * PB);
    unsigned short* Yl = Yh + (size_t)NB * DDSQ;
    float* Sc = ws + (size_t)10 * PB;

    hipMemsetAsync(Sc, 0, 2048 * sizeof(float), stream);

    u_kernel<<<dim3(IC, 4), 256, 0, stream>>>(caps, W, Up);
    cmb_kernel<<<512, 256, 0, stream>>>(Up, Xh, Xl, Sc);   // C (unscaled) -> X

    unsigned short* ph = Xh; unsigned short* pl = Xl;
    unsigned short* qh = Yh; unsigned short* ql = Yl;
    for (int it = 0; it < NSQ; ++it) {
        sqm_kernel<<<512, 256, 0, stream>>>(ph, pl, qh, ql,
                                            Sc + it * 64, Sc + (it + 1) * 64);
        unsigned short* t1 = ph; ph = qh; qh = t1;
        unsigned short* t2 = pl; pl = ql; ql = t2;
    }

    finish_kernel<<<NB, 256, 0, stream>>>(ph, pl, out);
}

// Round 7
// 404.727 us; speedup vs baseline: 1.9102x; 1.2983x over previous
//
#include <hip/hip_runtime.h>

#define NB  64
#define IC  2048
#define ID  16
#define DD  256
#define DDSQ 65536
#define PB  (DDSQ * NB)       // 4,194,304 floats = one full-batch fp32-sized buffer
#define NSQ 11                // matrix squarings
#define NPI 7                 // finish matvecs: exponent 2^11 * 8 = 16384

typedef __attribute__((ext_vector_type(8))) short          s16x8;  // 8 bf16 (4 VGPRs) MFMA frag
typedef __attribute__((ext_vector_type(4))) float          f32x4;  // MFMA acc
typedef __attribute__((ext_vector_type(4))) unsigned short us4;
typedef __attribute__((ext_vector_type(8))) unsigned short us8;

// fp32 -> bf16 (RNE) and back, via raw bits
__device__ __forceinline__ unsigned short f2b(float f) {
    union { float f; unsigned u; } c; c.f = f;
    const unsigned u = c.u + 0x7FFFu + ((c.u >> 16) & 1u);
    return (unsigned short)(u >> 16);
}
__device__ __forceinline__ float b2f(unsigned short h) {
    union { unsigned u; float f; } c; c.u = ((unsigned)h) << 16;
    return c.f;
}
// fp32 -> packed (hi bf16 << 16) | (lo bf16): 2-term split in one u32
__device__ __forceinline__ unsigned f2pk(float f) {
    const unsigned short h = f2b(f);
    const unsigned short l = f2b(f - b2f(h));
    return ((unsigned)h << 16) | (unsigned)l;
}

// ---------------- stage 1: u[b,c,:] = x[b,c,:] @ W_c (16 batches/block) -----
// output: PACKED u32 per element: (bf16_hi << 16) | bf16_lo
__global__ __launch_bounds__(256, 4) void u_kernel(const float* __restrict__ caps,
                                                   const float* __restrict__ W,
                                                   unsigned* __restrict__ U) {
    const int c  = blockIdx.x;
    const int b0 = blockIdx.y * 16;
    const int t  = threadIdx.x;
    __shared__ float xsT[ID][16];        // [dim][batch]
    if (t < 64) {
        const int b = t >> 2, q = (t & 3) * 4;
        const float4 x4 = *(const float4*)&caps[((size_t)(b0 + b) * IC + c) * ID + q];
        xsT[q + 0][b] = x4.x; xsT[q + 1][b] = x4.y;
        xsT[q + 2][b] = x4.z; xsT[q + 3][b] = x4.w;
    }
    __syncthreads();
    float a0 = 0.f, a1 = 0.f, a2 = 0.f, a3 = 0.f, a4 = 0.f, a5 = 0.f, a6 = 0.f, a7 = 0.f;
    float a8 = 0.f, a9 = 0.f, a10 = 0.f, a11 = 0.f, a12 = 0.f, a13 = 0.f, a14 = 0.f, a15 = 0.f;
#pragma unroll
    for (int i = 0; i < ID; ++i) {
        const float wi = W[((size_t)c * ID + i) * DD + t];    // coalesced over t
        const float4 x0 = *(const float4*)&xsT[i][0];
        const float4 x1 = *(const float4*)&xsT[i][4];
        const float4 x2 = *(const float4*)&xsT[i][8];
        const float4 x3 = *(const float4*)&xsT[i][12];
        a0  = fmaf(x0.x, wi, a0 );  a1  = fmaf(x0.y, wi, a1 );
        a2  = fmaf(x0.z, wi, a2 );  a3  = fmaf(x0.w, wi, a3 );
        a4  = fmaf(x1.x, wi, a4 );  a5  = fmaf(x1.y, wi, a5 );
        a6  = fmaf(x1.z, wi, a6 );  a7  = fmaf(x1.w, wi, a7 );
        a8  = fmaf(x2.x, wi, a8 );  a9  = fmaf(x2.y, wi, a9 );
        a10 = fmaf(x2.z, wi, a10);  a11 = fmaf(x2.w, wi, a11);
        a12 = fmaf(x3.x, wi, a12);  a13 = fmaf(x3.y, wi, a13);
        a14 = fmaf(x3.z, wi, a14);  a15 = fmaf(x3.w, wi, a15);
    }
    U[((size_t)(b0 +  0) * IC + c) * DD + t] = f2pk(a0);
    U[((size_t)(b0 +  1) * IC + c) * DD + t] = f2pk(a1);
    U[((size_t)(b0 +  2) * IC + c) * DD + t] = f2pk(a2);
    U[((size_t)(b0 +  3) * IC + c) * DD + t] = f2pk(a3);
    U[((size_t)(b0 +  4) * IC + c) * DD + t] = f2pk(a4);
    U[((size_t)(b0 +  5) * IC + c) * DD + t] = f2pk(a5);
    U[((size_t)(b0 +  6) * IC + c) * DD + t] = f2pk(a6);
    U[((size_t)(b0 +  7) * IC + c) * DD + t] = f2pk(a7);
    U[((size_t)(b0 +  8) * IC + c) * DD + t] = f2pk(a8);
    U[((size_t)(b0 +  9) * IC + c) * DD + t] = f2pk(a9);
    U[((size_t)(b0 + 10) * IC + c) * DD + t] = f2pk(a10);
    U[((size_t)(b0 + 11) * IC + c) * DD + t] = f2pk(a11);
    U[((size_t)(b0 + 12) * IC + c) * DD + t] = f2pk(a12);
    U[((size_t)(b0 + 13) * IC + c) * DD + t] = f2pk(a13);
    U[((size_t)(b0 + 14) * IC + c) * DD + t] = f2pk(a14);
    U[((size_t)(b0 + 15) * IC + c) * DD + t] = f2pk(a15);
}

// ---- stage 2: C = U^T U (full K), bf16 hi/lo out + trace, 512 blocks -------
// Register-transpose staging + T14 prefetch (proven clean rounds 4/6).
__global__ __launch_bounds__(256, 2)
void cmb_kernel(const unsigned* __restrict__ Up,
                unsigned short* __restrict__ Ch, unsigned short* __restrict__ Cl,
                float* __restrict__ Sc) {
    const int id   = blockIdx.x;
    const int bb   = id & 63;
    const int tile = id >> 6;            // 0..7 (2x4 of 128x64)
    const int tr = tile >> 2, tc = tile & 3;
    const int d0 = tr * 128, e0 = tc * 64;
    const int t    = threadIdx.x;
    const int lane = t & 63, wid = t >> 6;
    const int wm = wid >> 1, wn = wid & 1;            // 2x2 wave grid
    const int fr = lane & 15, kg = lane >> 4;         // frag row, k-group
    const int sl8 = lane & 7, qg = lane >> 3;         // staging: row-in-octet, k-quad
    const size_t mb = (size_t)bb * DDSQ;

    __shared__ unsigned short Ah[128][40];   // [d][k], pitch 40 shorts (80 B)
    __shared__ unsigned short Al[128][40];
    __shared__ unsigned short Bh[64][40];    // [e][k]
    __shared__ unsigned short Bl[64][40];
    __shared__ float red[256];

    const f32x4 z4 = {0.f, 0.f, 0.f, 0.f};
    f32x4 acc[4][2];
#pragma unroll
    for (int m = 0; m < 4; ++m)
#pragma unroll
        for (int n = 0; n < 2; ++n) acc[m][n] = z4;

    const unsigned* Ub = Up + (size_t)bb * IC * DD;
    unsigned va[4][4], vb[2][4];
    auto loadU = [&](int kb) {
#pragma unroll
        for (int s = 0; s < 4; ++s) {
            const int row = wid * 8 + sl8 + 32 * s;       // d-local 0..127
#pragma unroll
            for (int j = 0; j < 4; ++j)
                va[s][j] = Ub[(size_t)(kb + 4 * qg + j) * DD + d0 + row];
        }
#pragma unroll
        for (int s = 0; s < 2; ++s) {
            const int row = wid * 8 + sl8 + 32 * s;       // e-local 0..63
#pragma unroll
            for (int j = 0; j < 4; ++j)
                vb[s][j] = Ub[(size_t)(kb + 4 * qg + j) * DD + e0 + row];
        }
    };

    loadU(0);
    for (int kb = 0; kb < IC; kb += 32) {
        __syncthreads();
#pragma unroll
        for (int s = 0; s < 4; ++s) {
            const int row = wid * 8 + sl8 + 32 * s;
            us4 h, l;
#pragma unroll
            for (int j = 0; j < 4; ++j) {
                h[j] = (unsigned short)(va[s][j] >> 16);
                l[j] = (unsigned short)(va[s][j] & 0xFFFFu);
            }
            *(us4*)&Ah[row][4 * qg] = h;
            *(us4*)&Al[row][4 * qg] = l;
        }
#pragma unroll
        for (int s = 0; s < 2; ++s) {
            const int row = wid * 8 + sl8 + 32 * s;
            us4 h, l;
#pragma unroll
            for (int j = 0; j < 4; ++j) {
                h[j] = (unsigned short)(vb[s][j] >> 16);
                l[j] = (unsigned short)(vb[s][j] & 0xFFFFu);
            }
            *(us4*)&Bh[row][4 * qg] = h;
            *(us4*)&Bl[row][4 * qg] = l;
        }
        __syncthreads();
        if (kb + 32 < IC) loadU(kb + 32);     // T14: next loads fly under MFMA
        s16x8 ah[4], al[4], bh[2], bl[2];
#pragma unroll
        for (int m = 0; m < 4; ++m) {
            const int r = wm * 64 + m * 16 + fr;
            ah[m] = *(const s16x8*)&Ah[r][kg * 8];
            al[m] = *(const s16x8*)&Al[r][kg * 8];
        }
#pragma unroll
        for (int n = 0; n < 2; ++n) {
            const int r = wn * 32 + n * 16 + fr;
            bh[n] = *(const s16x8*)&Bh[r][kg * 8];
            bl[n] = *(const s16x8*)&Bl[r][kg * 8];
        }
#pragma unroll
        for (int m = 0; m < 4; ++m)
#pragma unroll
            for (int n = 0; n < 2; ++n) {
                acc[m][n] = __builtin_amdgcn_mfma_f32_16x16x32_bf16(ah[m], bh[n], acc[m][n], 0, 0, 0);
                acc[m][n] = __builtin_amdgcn_mfma_f32_16x16x32_bf16(ah[m], bl[n], acc[m][n], 0, 0, 0);
                acc[m][n] = __builtin_amdgcn_mfma_f32_16x16x32_bf16(al[m], bh[n], acc[m][n], 0, 0, 0);
            }
    }

    // epilogue: bf16 hi/lo store (UNSCALED C) + fp32 trace
    float ts = 0.f;
    const int row_l = wm * 64 + (lane >> 4) * 4;
    const int col_l = wn * 32 + fr;
#pragma unroll
    for (int m = 0; m < 4; ++m)
#pragma unroll
        for (int n = 0; n < 2; ++n)
#pragma unroll
            for (int r = 0; r < 4; ++r) {
                const int gr = d0 + row_l + m * 16 + r;
                const int gc = e0 + col_l + n * 16;
                const float e = acc[m][n][r];
                const unsigned short h = f2b(e);
                const unsigned short l = f2b(e - b2f(h));
                const size_t o = mb + (size_t)gr * DD + gc;
                Ch[o] = h; Cl[o] = l;
                if (gr == gc) ts += e;
            }
    if ((tc >> 1) == tr) {
        red[t] = ts;
        __syncthreads();
        for (int s2 = 128; s2 > 0; s2 >>= 1) {
            if (t < s2) red[t] += red[t + s2];
            __syncthreads();
        }
        if (t == 0) atomicAdd(&Sc[bb], red[0]);
    }
}

// ---- E = (D/s)^2 via bf16-split MFMA, 64x64 tile, 1024 blocks --------------
// Occupancy fix: 4 blocks/CU (16 waves/CU) vs 2 before — TLP hides load
// latency across the proven 2-barrier structure. Same k-order => bit-identical.
// D symmetric => B-panel rows e0..e0+63 give B[k][j] directly in [j][k].
__global__ __launch_bounds__(256, 4)
void sqm_kernel(const unsigned short* __restrict__ Dh, const unsigned short* __restrict__ Dl,
                unsigned short* __restrict__ Eh, unsigned short* __restrict__ El,
                const float* __restrict__ s_in, float* __restrict__ s_out) {
    const int id   = blockIdx.x;          // 1024 = 64 batches x 16 tiles
    const int bb   = id & 63;             // id%8 == bb%8 -> batch XCD-local
    const int tile = id >> 6;             // 0..15 (4x4 of 64x64)
    const int tr = tile >> 2, tc = tile & 3;
    const int d0 = tr * 64, e0 = tc * 64;
    const int t    = threadIdx.x;
    const int lane = t & 63, wid = t >> 6;
    const int wm = wid >> 1, wn = wid & 1;            // 2x2 wave grid, 32x32/wave
    const int fr = lane & 15, kg = lane >> 4;
    const size_t mb = (size_t)bb * DDSQ;

    __shared__ unsigned short Ah[64][40];   // pitch 40 shorts (80 B), proven
    __shared__ unsigned short Al[64][40];
    __shared__ unsigned short Bh[64][40];
    __shared__ unsigned short Bl[64][40];
    __shared__ float red[256];

    const f32x4 z4 = {0.f, 0.f, 0.f, 0.f};
    f32x4 acc[2][2];
#pragma unroll
    for (int m = 0; m < 2; ++m)
#pragma unroll
        for (int n = 0; n < 2; ++n) acc[m][n] = z4;

    const float s   = s_in[bb];
    const float inv = 1.f / (s * s);
    const int row = t >> 2, q = t & 3;    // staging map: 64 rows x 4 k-quads

    for (int kb = 0; kb < DD; kb += 32) {
        const size_t ga = mb + (size_t)(d0 + row) * DD + kb + q * 8;
        const size_t gb = mb + (size_t)(e0 + row) * DD + kb + q * 8;
        const int4 rah = *(const int4*)&Dh[ga];
        const int4 ral = *(const int4*)&Dl[ga];
        const int4 rbh = *(const int4*)&Dh[gb];
        const int4 rbl = *(const int4*)&Dl[gb];
        __syncthreads();
        *(int4*)&Ah[row][q * 8] = rah;
        *(int4*)&Al[row][q * 8] = ral;
        *(int4*)&Bh[row][q * 8] = rbh;
        *(int4*)&Bl[row][q * 8] = rbl;
        __syncthreads();

        s16x8 ah[2], al[2], bh[2], bl[2];
#pragma unroll
        for (int m = 0; m < 2; ++m) {
            const int r = wm * 32 + m * 16 + fr;
            ah[m] = *(const s16x8*)&Ah[r][kg * 8];
            al[m] = *(const s16x8*)&Al[r][kg * 8];
        }
#pragma unroll
        for (int n = 0; n < 2; ++n) {
            const int r = wn * 32 + n * 16 + fr;
            bh[n] = *(const s16x8*)&Bh[r][kg * 8];
            bl[n] = *(const s16x8*)&Bl[r][kg * 8];
        }
#pragma unroll
        for (int m = 0; m < 2; ++m)
#pragma unroll
            for (int n = 0; n < 2; ++n) {
                acc[m][n] = __builtin_amdgcn_mfma_f32_16x16x32_bf16(ah[m], bh[n], acc[m][n], 0, 0, 0);
                acc[m][n] = __builtin_amdgcn_mfma_f32_16x16x32_bf16(ah[m], bl[n], acc[m][n], 0, 0, 0);
                acc[m][n] = __builtin_amdgcn_mfma_f32_16x16x32_bf16(al[m], bh[n], acc[m][n], 0, 0, 0);
            }
    }

    // epilogue: scale, trace, split to hi/lo bf16
    float ts = 0.f;
    const int row_l = wm * 32 + (lane >> 4) * 4;
    const int col_l = wn * 32 + fr;
#pragma unroll
    for (int m = 0; m < 2; ++m)
#pragma unroll
        for (int n = 0; n < 2; ++n)
#pragma unroll
            for (int r = 0; r < 4; ++r) {
                const int gr = d0 + row_l + m * 16 + r;
                const int gc = e0 + col_l + n * 16;
                const float e = acc[m][n][r] * inv;
                const unsigned short h = f2b(e);
                const unsigned short l = f2b(e - b2f(h));
                const size_t o = mb + (size_t)gr * DD + gc;
                Eh[o] = h; El[o] = l;
                if (gr == gc) ts += e;
            }
    if (tr == tc) {                       // 64x64 diag tiles partition diagonal
        red[t] = ts;
        __syncthreads();
        for (int s2 = 128; s2 > 0; s2 >>= 1) {
            if (t < s2) red[t] += red[t + s2];
            __syncthreads();
        }
        if (t == 0) atomicAdd(&s_out[bb], red[0]);
    }
}

// ------- finish: column start + NPI matvecs (no renorm; lambda1 ~ 1) --------
__global__ __launch_bounds__(256, 2) void finish_kernel(const unsigned short* __restrict__ Dh,
                                                        const unsigned short* __restrict__ Dl,
                                                        float* __restrict__ out) {
    const int b = blockIdx.x, t = threadIdx.x;
    const size_t mb = (size_t)b * DDSQ;
    __shared__ float vs[DD];
    __shared__ float red[DD];
    __shared__ int   ridx[DD];
    red[t] = b2f(Dh[mb + (size_t)t * DD + t]) + b2f(Dl[mb + (size_t)t * DD + t]);
    ridx[t] = t;
    __syncthreads();
    for (int s = 128; s > 0; s >>= 1) {
        if (t < s && red[t + s] > red[t]) { red[t] = red[t + s]; ridx[t] = ridx[t + s]; }
        __syncthreads();
    }
    const int jmax0 = ridx[0];
    __syncthreads();
    float v = b2f(Dh[mb + (size_t)jmax0 * DD + t]) + b2f(Dl[mb + (size_t)jmax0 * DD + t]);
    for (int it = 0; it < NPI; ++it) {
        vs[t] = v;
        __syncthreads();
        float a = 0.f;
        const unsigned short* rh = Dh + mb + (size_t)t * DD;
        const unsigned short* rl = Dl + mb + (size_t)t * DD;
#pragma unroll 4
        for (int j = 0; j < DD; j += 8) {
            const us8 h8 = *(const us8*)&rh[j];
            const us8 l8 = *(const us8*)&rl[j];
            a = fmaf(b2f(h8[0]) + b2f(l8[0]), vs[j + 0], a);
            a = fmaf(b2f(h8[1]) + b2f(l8[1]), vs[j + 1], a);
            a = fmaf(b2f(h8[2]) + b2f(l8[2]), vs[j + 2], a);
            a = fmaf(b2f(h8[3]) + b2f(l8[3]), vs[j + 3], a);
            a = fmaf(b2f(h8[4]) + b2f(l8[4]), vs[j + 4], a);
            a = fmaf(b2f(h8[5]) + b2f(l8[5]), vs[j + 5], a);
            a = fmaf(b2f(h8[6]) + b2f(l8[6]), vs[j + 6], a);
            a = fmaf(b2f(h8[7]) + b2f(l8[7]), vs[j + 7], a);
        }
        __syncthreads();
        v = a;
    }
    vs[t] = v;
    red[t] = v * v;
    __syncthreads();
    for (int s = 128; s > 0; s >>= 1) {
        if (t < s) red[t] += red[t + s];
        __syncthreads();
    }
    const float nrm = sqrtf(red[0]);
    __syncthreads();
    red[t] = fabsf(v);
    ridx[t] = t;
    __syncthreads();
    for (int s = 128; s > 0; s >>= 1) {
        if (t < s && red[t + s] > red[t]) { red[t] = red[t + s]; ridx[t] = ridx[t + s]; }
        __syncthreads();
    }
    const float sgn = (vs[ridx[0]] < 0.f) ? -1.f : 1.f;
    out[(size_t)b * DD + t] = sgn * v / nrm;
}

extern "C" void kernel_launch(void* const* d_in, const int* in_sizes, int n_in,
                              void* d_out, int out_size, void* d_ws, size_t ws_size,
                              hipStream_t stream) {
    const float* caps = (const float*)d_in[0];   // (64, 2048, 16)
    const float* W    = (const float*)d_in[1];   // (2048, 16, 256)
    float* out = (float*)d_out;                  // (64, 256)
    float* ws  = (float*)d_ws;

    // layout: Up packed = 8*PB @0 | X @8PB | Y @9PB | Sc @10PB  (~168 MB)
    unsigned* Up = (unsigned*)ws;
    unsigned short* Xh = (unsigned short*)(ws + (size_t)8 * PB);
    unsigned short* Xl = Xh + (size_t)NB * DDSQ;
    unsigned short* Yh = (unsigned short*)(ws + (size_t)9 * PB);
    unsigned short* Yl = Yh + (size_t)NB * DDSQ;
    float* Sc = ws + (size_t)10 * PB;

    hipMemsetAsync(Sc, 0, 2048 * sizeof(float), stream);

    u_kernel<<<dim3(IC, 4), 256, 0, stream>>>(caps, W, Up);
    cmb_kernel<<<512, 256, 0, stream>>>(Up, Xh, Xl, Sc);   // C (unscaled) -> X

    unsigned short* ph = Xh; unsigned short* pl = Xl;
    unsigned short* qh = Yh; unsigned short* ql = Yl;
    for (int it = 0; it < NSQ; ++it) {
        sqm_kernel<<<1024, 256, 0, stream>>>(ph, pl, qh, ql,
                                             Sc + it * 64, Sc + (it + 1) * 64);
        unsigned short* t1 = ph; ph = qh; qh = t1;
        unsigned short* t2 = pl; pl = ql; ql = t2;
    }

    finish_kernel<<<NB, 256, 0, stream>>>(ph, pl, out);
}